// Round 8
// baseline (347.267 us; speedup 1.0000x reference)
//
#include <hip/hip_runtime.h>
#include <math.h>

// SimpleRetention bf16-MFMA pipeline, round 8.
// out = (softmax(QK^T) * gamma^|n-m|) @ V ; Q/K = xpos(X@W), V = X@Wv
// B=8 L=2048 H=Dh=1024.
//
// Round-8 change vs round-7 (one lever):
//  - gemm256p: 4-phase K-tile with counted vmcnt pipeline (T3+T4) + setprio
//    (T5). Stage granularity = K-half (16KB block); 2dbuf x 2kh ring per
//    operand; vmcnt(4) at phases P1/P3 (never 0 in loop); 2 raw barriers
//    per K-tile. Loads always have >=2 phases of flight time. Epilogues,
//    swizzle, and grid decodes identical to round 7.
//
// ws layout (169MB; phase-aliased):
//   [0,64MB)    Wmat bf16 [8][2048][2048]   (phase2; aliases Xb+WT of phase1)
//   [0,32MB)    Xb  bf16 [16384][1024]      (phase1)
//   [32,38MB)   WT  bf16 [3][1024][1024]    (phase1, W transposed)
//   [64,96MB)   Qb  bf16 [16384][1024]
//   [96,128MB)  Kb  bf16 [16384][1024]
//   [128,160MB) Vt  bf16 [8][1024][2048]    (V transposed per batch)
//   [160,160.5) Zp  f32  [8][8][2048]       (softmax denom partials)
//   [161,165MB) CSq u32  [2048][512]        (cos*scl_q | sin*scl_q bf16 pair)
//   [165,169MB) CSk u32  [2048][512]        (K: 1/scale)

#define LDIM 2048
#define HDIM 1024
#define MTOT 16384

typedef unsigned short u16;
typedef unsigned int u32;
typedef __attribute__((ext_vector_type(16))) float f32x16;
typedef __attribute__((ext_vector_type(8))) short s16x8;

#define GLD16(gp, lp) __builtin_amdgcn_global_load_lds( \
    (const __attribute__((address_space(1))) void*)(gp), \
    (__attribute__((address_space(3))) void*)(lp), 16, 0, 0)

__device__ __forceinline__ u16 f2bf(float f) {
    unsigned u = __float_as_uint(f);
    return (u16)((u + 0x7FFFu + ((u >> 16) & 1u)) >> 16);
}

// sin/cos(ang) via f64 revolution reduction + HW v_sin/v_cos (rev input).
__device__ __forceinline__ void sincos_rev(float ang, float* sn, float* cs) {
    double dr = (double)ang * 0.15915494309189535;   // 1/(2*pi)
    dr -= __builtin_floor(dr);
    float fr = (float)dr;
    float s_, c_;
    asm("v_sin_f32 %0, %1" : "=v"(s_) : "v"(fr));
    asm("v_cos_f32 %0, %1" : "=v"(c_) : "v"(fr));
    *sn = s_; *cs = c_;
}

// C/D mapping for mfma_f32_32x32x16_bf16 (HW-verified m74/m101):
//   col = lane&31, row = (reg&3) + 8*(reg>>2) + 4*(lane>>5), reg in [0,16)
#define ROW32(reg, laneHi) (((reg) & 3) + 8 * ((reg) >> 2) + 4 * (laneHi))

// ---------------------------------------------------------------------------
// gemm256p: 256x256 tile, BK=64, 512 thr = 8 waves (2m x 4n), wave C = 128x64
// = 4x2 frags of 32x32x16. 4-phase counted-vmcnt pipeline:
//   per K-half block: 16KB contiguous [256 rows][32 cols] (GLD16 linear dest).
//   LDS: A blocks (d*2+kh)*16KB at [0,64K); B same at [64K,128K).
//   Phase p of tile t(d): { ds_read frags(ks=p); stage half into dbuf e;
//     [P1/P3: vmcnt(4)+s_barrier]; setprio(1); 8 MFMA; setprio(0) }.
//   Stage order A-kh0,B-kh0,A-kh1,B-kh1 per tile; vmcnt(4) at P1 confirms
//   kh1(t) (needed P2/P3); at P3 confirms kh0(t+1) (needed next P0/P1);
//   4 loads (2 halves) always in flight. Last tile peeled (vmcnt 0 there).
//   Swizzle: slot' = slot ^ (row&3) within 64B rows, inverse on GLD source.
// ---------------------------------------------------------------------------
__device__ __forceinline__ void gemm256p(const u16* __restrict__ A,
                                         const u16* __restrict__ B,
                                         int lda, int ldb, int K, int m0, int n0,
                                         char* smem, int tid, f32x16 (*acc)[2])
{
    const int wv = tid >> 6, ln = tid & 63;
    const int wm = wv >> 2, wn = wv & 3;
    const int lane31 = ln & 31, laneHi = ln >> 5;

    // staging: thread -> row (tid>>2), slot (tid&3); source col inverse-swizzled
    const int srow = tid >> 2;                       // 0..127
    const int scol = ((tid & 3) ^ (srow & 3)) * 8;   // elements
    const u16* ap0 = A + (size_t)(m0 + srow) * lda + scol;
    const u16* ap1 = A + (size_t)(m0 + 128 + srow) * lda + scol;
    const u16* bp0 = B + (size_t)(n0 + srow) * ldb + scol;
    const u16* bp1 = B + (size_t)(n0 + 128 + srow) * ldb + scol;
    int ak = 0, bk = 0;   // advancing k-offset (elements), +32 per half staged

    // fragment read row bases (byte) and row&3 for swizzle
    int arb[4], ar3[4];
#pragma unroll
    for (int fm = 0; fm < 4; ++fm) {
        const int r = wm * 128 + fm * 32 + lane31;
        arb[fm] = r * 64; ar3[fm] = r & 3;
    }
    int brb[2], br3[2];
#pragma unroll
    for (int fn = 0; fn < 2; ++fn) {
        const int r = wn * 64 + fn * 32 + lane31;
        brb[fn] = r * 64; br3[fn] = r & 3;
    }

#define STAGE_A(blk) do { char* d_ = smem + (blk) * 16384 + tid * 16;         \
        GLD16(ap0 + ak, d_); GLD16(ap1 + ak, d_ + 8192); ak += 32; } while (0)
#define STAGE_B(blk) do { char* d_ = smem + 65536 + (blk) * 16384 + tid * 16; \
        GLD16(bp0 + bk, d_); GLD16(bp1 + bk, d_ + 8192); bk += 32; } while (0)

#define READS(d, ks, af, bf) do {                                             \
        const char* Ab_ = smem + ((d) * 2 + ((ks) >> 1)) * 16384;             \
        const char* Bb_ = Ab_ + 65536;                                        \
        const int sl_ = (((ks) & 1) << 1) | laneHi;                           \
        _Pragma("unroll") for (int fm_ = 0; fm_ < 4; ++fm_)                   \
            af[fm_] = *(const s16x8*)(Ab_ + arb[fm_] + ((sl_ ^ ar3[fm_]) << 4)); \
        _Pragma("unroll") for (int fn_ = 0; fn_ < 2; ++fn_)                   \
            bf[fn_] = *(const s16x8*)(Bb_ + brb[fn_] + ((sl_ ^ br3[fn_]) << 4)); \
    } while (0)

#define MFMA8(af, bf) do {                                                    \
        __builtin_amdgcn_s_setprio(1);                                        \
        _Pragma("unroll") for (int fm_ = 0; fm_ < 4; ++fm_)                   \
            _Pragma("unroll") for (int fn_ = 0; fn_ < 2; ++fn_)               \
                acc[fm_][fn_] = __builtin_amdgcn_mfma_f32_32x32x16_bf16(      \
                    af[fm_], bf[fn_], acc[fm_][fn_], 0, 0, 0);                \
        __builtin_amdgcn_s_setprio(0);                                        \
    } while (0)

#define WAITBAR(n) do {                                                      \
        asm volatile("s_waitcnt vmcnt(" #n ")" ::: "memory");                 \
        __builtin_amdgcn_s_barrier();                                         \
        __builtin_amdgcn_sched_barrier(0); } while (0)

    const int nk = K >> 6;

    // prologue: stage tile 0 (order A0,B0,A1,B1); confirm kh0 resident.
    STAGE_A(0); STAGE_B(0); STAGE_A(1); STAGE_B(1);
    WAITBAR(4);

#pragma unroll 1
    for (int t = 0; t < nk - 1; ++t) {
        const int d = t & 1, e = d ^ 1;
        s16x8 af[4], bf[2];
        // P0: reads ks0 (kh0(t), resident); stage A-kh0(t+1); MFMA
        READS(d, 0, af, bf); STAGE_A(e * 2 + 0);            MFMA8(af, bf);
        // P1: reads ks1; stage B-kh0(t+1); confirm kh1(t); MFMA
        READS(d, 1, af, bf); STAGE_B(e * 2 + 0); WAITBAR(4); MFMA8(af, bf);
        // P2: reads ks2 (kh1(t)); stage A-kh1(t+1); MFMA
        READS(d, 2, af, bf); STAGE_A(e * 2 + 1);            MFMA8(af, bf);
        // P3: reads ks3; stage B-kh1(t+1); confirm kh0(t+1); MFMA
        READS(d, 3, af, bf); STAGE_B(e * 2 + 1); WAITBAR(4); MFMA8(af, bf);
    }
    {   // peeled last tile (no stages; drain remaining kh1 at P1)
        const int d = (nk - 1) & 1;
        s16x8 af[4], bf[2];
        READS(d, 0, af, bf);              MFMA8(af, bf);
        READS(d, 1, af, bf); WAITBAR(0);  MFMA8(af, bf);
        READS(d, 2, af, bf);              MFMA8(af, bf);
        READS(d, 3, af, bf);              MFMA8(af, bf);
    }
    __syncthreads();   // epilogue may reuse smem
#undef STAGE_A
#undef STAGE_B
#undef READS
#undef MFMA8
#undef WAITBAR
}

// ---------------------------------------------------------------------------
// prep: xpos tables. CS*[l][ih] = pack_bf16(cos(l*invf)*scl, sin(l*invf)*scl)
// ---------------------------------------------------------------------------
__global__ __launch_bounds__(256) void gen_tab(u32* __restrict__ CSq,
                                               u32* __restrict__ CSk)
{
    const int l = blockIdx.x;
    for (int ih = threadIdx.x; ih < 512; ih += 256) {
        float invf = exp2f(-13.287712379549449f * (1.f / 512.f) * (float)ih);
        float sn, cs;
        sincos_rev((float)l * invf, &sn, &cs);
        float l2sv = log2f(((float)(2 * ih) + 409.6f) * (1.f / 1433.6f));
        float e = (float)l * (1.f / 512.f) * l2sv;
        float sq = exp2f(e), sk = exp2f(-e);
        CSq[l * 512 + ih] = (u32)f2bf(cs * sq) | ((u32)f2bf(sn * sq) << 16);
        CSk[l * 512 + ih] = (u32)f2bf(cs * sk) | ((u32)f2bf(sn * sk) << 16);
    }
}

// ---------------------------------------------------------------------------
// prep: X -> bf16
// ---------------------------------------------------------------------------
__global__ __launch_bounds__(256) void cast_x(const float* __restrict__ X,
                                              u16* __restrict__ Xb, int n4)
{
    int i = blockIdx.x * 256 + threadIdx.x;
    const int stride = gridDim.x * 256;
    for (; i < n4; i += stride) {
        float4 v = ((const float4*)X)[i];
        ushort4 o = make_ushort4(f2bf(v.x), f2bf(v.y), f2bf(v.z), f2bf(v.w));
        ((ushort4*)Xb)[i] = o;
    }
}

// ---------------------------------------------------------------------------
// prep: W (1024x1024 f32, [k][n]) -> WT bf16 [n][k], for z in {Q,K,V}
// ---------------------------------------------------------------------------
__global__ __launch_bounds__(256) void transw(const float* __restrict__ Wq,
                                              const float* __restrict__ Wk,
                                              const float* __restrict__ Wv,
                                              u16* __restrict__ WT)
{
    __shared__ float L[64][65];
    const int z = blockIdx.z;
    const float* Wz = (z == 0) ? Wq : (z == 1) ? Wk : Wv;
    u16* Oz = WT + (size_t)z * HDIM * HDIM;
    const int k0 = blockIdx.y * 64, n0 = blockIdx.x * 64;
    const int t = threadIdx.x;
    const int r_ = t >> 4, c4 = (t & 15) * 4;
#pragma unroll
    for (int it = 0; it < 4; ++it) {
        const int row = it * 16 + r_;
        float4 v = *(const float4*)&Wz[(size_t)(k0 + row) * HDIM + n0 + c4];
        L[row][c4 + 0] = v.x; L[row][c4 + 1] = v.y;
        L[row][c4 + 2] = v.z; L[row][c4 + 3] = v.w;
    }
    __syncthreads();
#pragma unroll
    for (int it = 0; it < 4; ++it) {
        const int orow = it * 16 + r_;   // n-local
        ushort4 o = make_ushort4(f2bf(L[c4 + 0][orow]), f2bf(L[c4 + 1][orow]),
                                 f2bf(L[c4 + 2][orow]), f2bf(L[c4 + 3][orow]));
        *(ushort4*)&Oz[(size_t)(n0 + orow) * HDIM + k0 + c4] = o;
    }
}

// ---------------------------------------------------------------------------
// K1: {Q,K,V} = X@W, xpos fused via tables for Q/K, V stored transposed.
// grid 768 x 512thr. decode: xcd(8) | m8(8) n(4) z(3); xcd owns batch xcd
// (2048 rows = 4MB X-chunk hot in its L2 across the n x z sweep).
// ---------------------------------------------------------------------------
__global__ __launch_bounds__(512, 2) void qkv_gemm(
    const u16* __restrict__ Xb, const u16* __restrict__ WT,
    const u32* __restrict__ CSq, const u32* __restrict__ CSk,
    u16* __restrict__ Qb, u16* __restrict__ Kb, u16* __restrict__ Vt)
{
    __shared__ __align__(16) char smem[256 * 264 * 2];   // 135168 >= 131072
    const int bid = blockIdx.x;
    const int xcd = bid & 7, t = bid >> 3;   // t in [0,96)
    const int m8 = t & 7;
    const int n_ = (t >> 3) & 3;
    const int z  = t >> 5;
    const int m0 = (xcd * 8 + m8) * 256;
    const int n0 = n_ * 256;
    const int tid = threadIdx.x;

    f32x16 acc[4][2] = {};

    gemm256p(Xb, WT + (size_t)z * HDIM * HDIM, HDIM, HDIM, HDIM, m0, n0, smem, tid, acc);

    const int wv = tid >> 6, ln = tid & 63;
    const int wm = wv >> 2, wn = wv & 3;
    const int lane31 = ln & 31, laneHi = ln >> 5;
    const int l0 = m0 & (LDIM - 1);
    u16* T = (u16*)smem;   // [256][264]

    if (z < 2) {
        const u32* CS = (z == 0) ? CSq : CSk;
#pragma unroll
        for (int fn = 0; fn < 2; ++fn) {
            const int gc = n0 + wn * 64 + fn * 32 + lane31;
            const int ih = gc >> 1;
            const float sgn = (gc & 1) ? 1.f : -1.f;
            const u32* tb = CS + (size_t)l0 * 512 + ih;
#pragma unroll
            for (int fm = 0; fm < 4; ++fm) {
#pragma unroll
                for (int reg = 0; reg < 16; ++reg) {
                    const int rowl = wm * 128 + fm * 32 + ROW32(reg, laneHi);
                    u32 v = tb[(size_t)rowl * 512];
                    float cs = __uint_as_float(v << 16);
                    float sn = __uint_as_float(v & 0xFFFF0000u);
                    float c = acc[fm][fn][reg];
                    float p = __shfl_xor(c, 1);   // even<->odd column partner
                    T[rowl * 264 + wn * 64 + fn * 32 + lane31] =
                        f2bf(c * cs + sgn * p * sn);
                }
            }
        }
        __syncthreads();
        u16* Out = (z == 0) ? Qb : Kb;
        const int row_ = tid >> 5, slot = tid & 31;
#pragma unroll
        for (int g = 0; g < 16; ++g) {
            const int row = g * 16 + row_;
            s16x8 v = *(const s16x8*)&T[row * 264 + slot * 8];
            *(s16x8*)&Out[(size_t)(m0 + row) * HDIM + n0 + slot * 8] = v;
        }
    } else {
        // V: repack transposed  T[n_local][m_local]
#pragma unroll
        for (int fn = 0; fn < 2; ++fn)
#pragma unroll
            for (int fm = 0; fm < 4; ++fm)
#pragma unroll
                for (int reg = 0; reg < 16; ++reg)
                    T[(wn * 64 + fn * 32 + lane31) * 264 +
                      wm * 128 + fm * 32 + ROW32(reg, laneHi)] =
                        f2bf(acc[fm][fn][reg]);
        __syncthreads();
        const int b = m0 >> 11;
        const int row_ = tid >> 5, slot = tid & 31;
#pragma unroll
        for (int g = 0; g < 16; ++g) {
            const int row = g * 16 + row_;   // n-local (d index)
            s16x8 v = *(const s16x8*)&T[row * 264 + slot * 8];
            *(s16x8*)&Vt[((size_t)b * HDIM + n0 + row) * LDIM + l0 + slot * 8] = v;
        }
    }
}

// ---------------------------------------------------------------------------
// K2a: W = exp(s)*gamma^|q-k| (bf16) + Z partials (fp32, deterministic).
// grid 512 x 512thr: b = bid&7 (XCD-pinned). decode: nt(8) mt(8) --
// 4MB Q_b hot in XCD L2 across the nt sweep.
// ---------------------------------------------------------------------------
__global__ __launch_bounds__(512, 2) void qk_gemm(
    const u16* __restrict__ Q, const u16* __restrict__ Km,
    u16* __restrict__ Wm, float* __restrict__ Zp)
{
    __shared__ __align__(16) char smem[256 * 264 * 2];
    __shared__ float Zl[4][256];
    const int bid = blockIdx.x;
    const int b = bid & 7, t = bid >> 3;     // t in [0,64)
    const int mt = t & 7;
    const int nt = t >> 3;                   // [0,8)
    const int m0 = mt * 256;
    const int n0 = nt * 256;
    const int tid = threadIdx.x;

    f32x16 acc[4][2] = {};

    gemm256p(Q + (size_t)b * LDIM * HDIM, Km + (size_t)b * LDIM * HDIM,
             HDIM, HDIM, HDIM, m0, n0, smem, tid, acc);

    const int wv = tid >> 6, ln = tid & 63;
    const int wm = wv >> 2, wn = wv & 3;
    const int lane31 = ln & 31, laneHi = ln >> 5;
    u16* T = (u16*)smem;   // [256][264]
    const float LOG2E = 1.4426950408889634f;
    const float LOG2G = -0.15200309344504997f;   // log2(0.9)

#pragma unroll
    for (int fm = 0; fm < 4; ++fm) {
        float ps[16];
#pragma unroll
        for (int reg = 0; reg < 16; ++reg) ps[reg] = 0.f;
#pragma unroll
        for (int fn = 0; fn < 2; ++fn) {
            const int gk = n0 + wn * 64 + fn * 32 + lane31;
#pragma unroll
            for (int reg = 0; reg < 16; ++reg) {
                const int mloc = wm * 128 + fm * 32 + ROW32(reg, laneHi);
                const int gq = m0 + mloc;
                float t1 = acc[fm][fn][reg] * LOG2E;
                float e = exp2f(t1);
                int dd = gq - gk; dd = dd < 0 ? -dd : dd;
                ps[reg] += e;
                T[mloc * 264 + wn * 64 + fn * 32 + lane31] =
                    f2bf(exp2f(t1 + (float)dd * LOG2G));
            }
        }
        // reduce e-sums across the 32 column-lanes
#pragma unroll
        for (int reg = 0; reg < 16; ++reg) {
            float s = ps[reg];
            s += __shfl_xor(s, 1); s += __shfl_xor(s, 2);
            s += __shfl_xor(s, 4); s += __shfl_xor(s, 8);
            s += __shfl_xor(s, 16);
            if (lane31 == 0)
                Zl[wn][wm * 128 + fm * 32 + ROW32(reg, laneHi)] = s;
        }
    }
    __syncthreads();

    const int row_ = tid >> 5, slot = tid & 31;
#pragma unroll
    for (int g = 0; g < 16; ++g) {
        const int row = g * 16 + row_;
        s16x8 v = *(const s16x8*)&T[row * 264 + slot * 8];
        *(s16x8*)&Wm[((size_t)b * LDIM + m0 + row) * LDIM + n0 + slot * 8] = v;
    }
    if (tid < 256)
        Zp[((size_t)b * 8 + nt) * LDIM + m0 + tid] =
            Zl[0][tid] + Zl[1][tid] + Zl[2][tid] + Zl[3][tid];
}

// ---------------------------------------------------------------------------
// K2b: O = (W @ V) / Z  (fp32 out).  grid 256 x 512thr: b=bid&7.
// decode: mtH(2) nt(4) mt4(4) -- 4MB W-chunk hot across the nt sweep.
// ---------------------------------------------------------------------------
__global__ __launch_bounds__(512, 2) void pv_gemm(
    const u16* __restrict__ Wm, const u16* __restrict__ Vt,
    const float* __restrict__ Zp, float* __restrict__ Out)
{
    __shared__ __align__(16) char smem[2 * 65536];
    __shared__ float Zinv[256];
    const int bid = blockIdx.x;
    const int b = bid & 7, t = bid >> 3;     // t in [0,32)
    const int mt4 = t & 3;
    const int nt = (t >> 2) & 3;
    const int mtH = t >> 4;                  // {0,1}
    const int m0 = (mtH * 4 + mt4) * 256;
    const int n0 = nt * 256;
    const int tid = threadIdx.x;

    if (tid < 256) {
        float zz = 0.f;
#pragma unroll
        for (int nb = 0; nb < 8; ++nb)
            zz += Zp[((size_t)b * 8 + nb) * LDIM + m0 + tid];
        Zinv[tid] = 1.0f / zz;
    }
    __syncthreads();   // drains Zp loads: core's vmcnt counting starts clean

    f32x16 acc[4][2] = {};

    gemm256p(Wm + (size_t)b * LDIM * LDIM, Vt + (size_t)b * HDIM * LDIM,
             LDIM, LDIM, LDIM, m0, n0, smem, tid, acc);

    const int wv = tid >> 6, ln = tid & 63;
    const int wm = wv >> 2, wn = wv & 3;
    const int lane31 = ln & 31, laneHi = ln >> 5;
    float* Ob = Out + (size_t)b * LDIM * HDIM;
#pragma unroll
    for (int fm = 0; fm < 4; ++fm)
#pragma unroll
        for (int fn = 0; fn < 2; ++fn) {
            const int gn = n0 + wn * 64 + fn * 32 + lane31;
#pragma unroll
            for (int reg = 0; reg < 16; ++reg) {
                const int row = wm * 128 + fm * 32 + ROW32(reg, laneHi);
                Ob[(size_t)(m0 + row) * HDIM + gn] = acc[fm][fn][reg] * Zinv[row];
            }
        }
}

// ---------------------------------------------------------------------------
extern "C" void kernel_launch(void* const* d_in, const int* in_sizes, int n_in,
                              void* d_out, int out_size, void* d_ws, size_t ws_size,
                              hipStream_t stream)
{
    (void)in_sizes; (void)n_in; (void)out_size; (void)ws_size;
    const float* X  = (const float*)d_in[0];
    const float* Wq = (const float*)d_in[1];
    const float* Wk = (const float*)d_in[2];
    const float* Wv = (const float*)d_in[3];
    char* ws = (char*)d_ws;
    const size_t MB = 1024 * 1024;

    u16* Wmat = (u16*)ws;                 // phase2, aliases Xb+WT
    u16* Xb   = (u16*)ws;                 // phase1
    u16* WT   = (u16*)(ws + 32 * MB);     // phase1
    u16* Qb   = (u16*)(ws + 64 * MB);
    u16* Kb   = (u16*)(ws + 96 * MB);
    u16* Vt   = (u16*)(ws + 128 * MB);
    float* Zp = (float*)(ws + 160 * MB);
    u32* CSq  = (u32*)(ws + 161 * MB);
    u32* CSk  = (u32*)(ws + 165 * MB);

    gen_tab<<<2048, 256, 0, stream>>>(CSq, CSk);
    cast_x<<<2048, 256, 0, stream>>>(X, Xb, MTOT * HDIM / 4);
    transw<<<dim3(16, 16, 3), 256, 0, stream>>>(Wq, Wk, Wv, WT);
    qkv_gemm<<<768, 512, 0, stream>>>(Xb, WT, CSq, CSk, Qb, Kb, Vt);
    qk_gemm<<<512, 512, 0, stream>>>(Qb, Kb, Wmat, Zp);
    pv_gemm<<<256, 512, 0, stream>>>(Wmat, Vt, Zp, (float*)d_out);
}

// Round 9
// 323.091 us; speedup vs baseline: 1.0748x; 1.0748x over previous
//
#include <hip/hip_runtime.h>
#include <math.h>

// SimpleRetention bf16-MFMA pipeline, round 9.
// out = (softmax(QK^T) * gamma^|n-m|) @ V ; Q/K = xpos(X@W), V = X@Wv
// B=8 L=2048 H=Dh=1024.
//
// Round-9 changes vs round-8:
//  - REVERT gemm core to round-7 gemm256 (r8's K-half staging shrank LDS rows
//    to 64B -> 4 slots -> 2x bank aliasing; conflicts 9.7e6 -> 2.9e7, -11%).
//    r7's 128B-row/8-slot swizzle is at the conflict-free minimum.
//  - Merge gen_tab + cast_x + transw into one prep kernel (2 fewer launches).
//
// ws layout (169MB; phase-aliased):
//   [0,64MB)    Wmat bf16 [8][2048][2048]   (phase2; aliases Xb+WT of phase1)
//   [0,32MB)    Xb  bf16 [16384][1024]      (phase1)
//   [32,38MB)   WT  bf16 [3][1024][1024]    (phase1, W transposed)
//   [64,96MB)   Qb  bf16 [16384][1024]
//   [96,128MB)  Kb  bf16 [16384][1024]
//   [128,160MB) Vt  bf16 [8][1024][2048]    (V transposed per batch)
//   [160,160.5) Zp  f32  [8][8][2048]       (softmax denom partials)
//   [161,165MB) CSq u32  [2048][512]        (cos*scl_q | sin*scl_q bf16 pair)
//   [165,169MB) CSk u32  [2048][512]        (K: 1/scale)

#define LDIM 2048
#define HDIM 1024
#define MTOT 16384

typedef unsigned short u16;
typedef unsigned int u32;
typedef __attribute__((ext_vector_type(16))) float f32x16;
typedef __attribute__((ext_vector_type(8))) short s16x8;

#define GLD16(gp, lp) __builtin_amdgcn_global_load_lds( \
    (const __attribute__((address_space(1))) void*)(gp), \
    (__attribute__((address_space(3))) void*)(lp), 16, 0, 0)

__device__ __forceinline__ u16 f2bf(float f) {
    unsigned u = __float_as_uint(f);
    return (u16)((u + 0x7FFFu + ((u >> 16) & 1u)) >> 16);
}

// sin/cos(ang) via f64 revolution reduction + HW v_sin/v_cos (rev input).
__device__ __forceinline__ void sincos_rev(float ang, float* sn, float* cs) {
    double dr = (double)ang * 0.15915494309189535;   // 1/(2*pi)
    dr -= __builtin_floor(dr);
    float fr = (float)dr;
    float s_, c_;
    asm("v_sin_f32 %0, %1" : "=v"(s_) : "v"(fr));
    asm("v_cos_f32 %0, %1" : "=v"(c_) : "v"(fr));
    *sn = s_; *cs = c_;
}

// C/D mapping for mfma_f32_32x32x16_bf16 (HW-verified m74/m101):
//   col = lane&31, row = (reg&3) + 8*(reg>>2) + 4*(lane>>5), reg in [0,16)
#define ROW32(reg, laneHi) (((reg) & 3) + 8 * ((reg) >> 2) + 4 * (laneHi))

// ---------------------------------------------------------------------------
// gemm256 (round-7 core, verbatim): 256x256 tile, BK=64, 512 thr = 8 waves
// (2m x 4n), wave C = 128x64 = 4x2 frags of 32x32x16. Double-buffered LDS
// 2 x 64KB; stage of tile t+1 issued at top of iter t. XOR-swizzle
// slot' = slot ^ (row&7) on 128B rows (bank = slot only: conflict-free min),
// inverse-applied on GLD16 source. C = A x B^T (both row-major).
// ---------------------------------------------------------------------------
__device__ __forceinline__ void gemm256(const u16* __restrict__ A,
                                        const u16* __restrict__ B,
                                        int lda, int ldb, int K, int m0, int n0,
                                        char* smem, int tid, f32x16 (*acc)[2])
{
    const int wv = tid >> 6, ln = tid & 63;
    const int wm = wv >> 2, wn = wv & 3;
    const int lane31 = ln & 31, laneHi = ln >> 5;
    const int srow = tid >> 3;                        // 0..63 staging row/round
    const int scol = ((tid & 7) ^ (srow & 7)) * 8;    // inverse-swizzled source

    // incremental per-thread global source pointers (advance 64 elems/tile)
    const u16* ap[4];
    const u16* bp[4];
#pragma unroll
    for (int r = 0; r < 4; ++r) {
        ap[r] = A + (size_t)(m0 + r * 64 + srow) * lda + scol;
        bp[r] = B + (size_t)(n0 + r * 64 + srow) * ldb + scol;
    }

    // swizzled LDS fragment base byte offsets; per-ks XOR (ks<<5)
    int abyte[4], bbyte[2];
    const int slot_r = (laneHi ^ (lane31 & 7)) << 4;
#pragma unroll
    for (int fm = 0; fm < 4; ++fm)
        abyte[fm] = (wm * 128 + fm * 32 + lane31) * 128 + slot_r;
#pragma unroll
    for (int fn = 0; fn < 2; ++fn)
        bbyte[fn] = 32768 + (wn * 64 + fn * 32 + lane31) * 128 + slot_r;

#define STAGE256(sl) do {                                                  \
        char* d_ = smem + (sl) * 65536;                                    \
        _Pragma("unroll")                                                  \
        for (int r_ = 0; r_ < 4; ++r_) {                                   \
            GLD16(ap[r_], d_ + r_ * 8192 + tid * 16);                      \
            ap[r_] += 64;                                                  \
        }                                                                  \
        _Pragma("unroll")                                                  \
        for (int r_ = 0; r_ < 4; ++r_) {                                   \
            GLD16(bp[r_], d_ + 32768 + r_ * 8192 + tid * 16);              \
            bp[r_] += 64;                                                  \
        }                                                                  \
    } while (0)

    const int nk = K >> 6;
    STAGE256(0);
    __syncthreads();                    // tile 0 resident

    int buf = 0;
#pragma unroll 1
    for (int t = 0; t < nk; ++t) {
        if (t + 1 < nk) STAGE256(buf ^ 1);   // issued early: full tile of slack
        const char* Bb = smem + buf * 65536;
#pragma unroll
        for (int ks = 0; ks < 4; ++ks) {
            s16x8 af[4], bf[2];
#pragma unroll
            for (int fm = 0; fm < 4; ++fm)
                af[fm] = *(const s16x8*)(Bb + (abyte[fm] ^ (ks << 5)));
#pragma unroll
            for (int fn = 0; fn < 2; ++fn)
                bf[fn] = *(const s16x8*)(Bb + (bbyte[fn] ^ (ks << 5)));
#pragma unroll
            for (int fm = 0; fm < 4; ++fm)
#pragma unroll
                for (int fn = 0; fn < 2; ++fn)
                    acc[fm][fn] = __builtin_amdgcn_mfma_f32_32x32x16_bf16(
                        af[fm], bf[fn], acc[fm][fn], 0, 0, 0);
        }
        __syncthreads();   // drains vmcnt (t+1 resident) + orders buf reuse
        buf ^= 1;
    }
#undef STAGE256
}

// ---------------------------------------------------------------------------
// prep_all: one launch, three jobs by block range.
//   [0,2048)     cast_x:  X f32 -> Xb bf16 (grid-stride over 16M/4 float4s)
//   [2048,4096)  gen_tab: xpos cos/sin*scale tables (l = bid-2048)
//   [4096,4864)  transw:  W [k][n] f32 -> WT bf16 [n][k], 64x64 tiles
// ---------------------------------------------------------------------------
__global__ __launch_bounds__(256) void prep_all(
    const float* __restrict__ X,
    const float* __restrict__ Wq, const float* __restrict__ Wk,
    const float* __restrict__ Wv,
    u16* __restrict__ Xb, u16* __restrict__ WT,
    u32* __restrict__ CSq, u32* __restrict__ CSk)
{
    __shared__ float L[64][65];
    const int bid = blockIdx.x;
    if (bid < 2048) {
        const int n4 = MTOT * HDIM / 4;
        int i = bid * 256 + threadIdx.x;
        const int stride = 2048 * 256;
        for (; i < n4; i += stride) {
            float4 v = ((const float4*)X)[i];
            ushort4 o = make_ushort4(f2bf(v.x), f2bf(v.y), f2bf(v.z), f2bf(v.w));
            ((ushort4*)Xb)[i] = o;
        }
    } else if (bid < 4096) {
        const int l = bid - 2048;
        for (int ih = threadIdx.x; ih < 512; ih += 256) {
            float invf = exp2f(-13.287712379549449f * (1.f / 512.f) * (float)ih);
            float sn, cs;
            sincos_rev((float)l * invf, &sn, &cs);
            float l2sv = log2f(((float)(2 * ih) + 409.6f) * (1.f / 1433.6f));
            float e = (float)l * (1.f / 512.f) * l2sv;
            float sq = exp2f(e), sk = exp2f(-e);
            CSq[l * 512 + ih] = (u32)f2bf(cs * sq) | ((u32)f2bf(sn * sq) << 16);
            CSk[l * 512 + ih] = (u32)f2bf(cs * sk) | ((u32)f2bf(sn * sk) << 16);
        }
    } else {
        const int r = bid - 4096;            // [0,768) = 3 z x 16 y x 16 x
        const int z = r >> 8;
        const int y = (r >> 4) & 15;
        const int x = r & 15;
        const float* Wz = (z == 0) ? Wq : (z == 1) ? Wk : Wv;
        u16* Oz = WT + (size_t)z * HDIM * HDIM;
        const int k0 = y * 64, n0 = x * 64;
        const int t = threadIdx.x;
        const int r_ = t >> 4, c4 = (t & 15) * 4;
#pragma unroll
        for (int it = 0; it < 4; ++it) {
            const int row = it * 16 + r_;
            float4 v = *(const float4*)&Wz[(size_t)(k0 + row) * HDIM + n0 + c4];
            L[row][c4 + 0] = v.x; L[row][c4 + 1] = v.y;
            L[row][c4 + 2] = v.z; L[row][c4 + 3] = v.w;
        }
        __syncthreads();
#pragma unroll
        for (int it = 0; it < 4; ++it) {
            const int orow = it * 16 + r_;   // n-local
            ushort4 o = make_ushort4(f2bf(L[c4 + 0][orow]), f2bf(L[c4 + 1][orow]),
                                     f2bf(L[c4 + 2][orow]), f2bf(L[c4 + 3][orow]));
            *(ushort4*)&Oz[(size_t)(n0 + orow) * HDIM + k0 + c4] = o;
        }
    }
}

// ---------------------------------------------------------------------------
// K1: {Q,K,V} = X@W, xpos fused via tables for Q/K, V stored transposed.
// grid 768 x 512thr. decode: xcd(8) | m8(8) n(4) z(3); xcd owns batch xcd
// (2048 rows = 4MB X-chunk hot in its L2 across the n x z sweep).
// ---------------------------------------------------------------------------
__global__ __launch_bounds__(512, 2) void qkv_gemm(
    const u16* __restrict__ Xb, const u16* __restrict__ WT,
    const u32* __restrict__ CSq, const u32* __restrict__ CSk,
    u16* __restrict__ Qb, u16* __restrict__ Kb, u16* __restrict__ Vt)
{
    __shared__ __align__(16) char smem[256 * 264 * 2];   // >= 2*65536 ring
    const int bid = blockIdx.x;
    const int xcd = bid & 7, t = bid >> 3;   // t in [0,96)
    const int m8 = t & 7;
    const int n_ = (t >> 3) & 3;
    const int z  = t >> 5;
    const int m0 = (xcd * 8 + m8) * 256;
    const int n0 = n_ * 256;
    const int tid = threadIdx.x;

    f32x16 acc[4][2] = {};

    gemm256(Xb, WT + (size_t)z * HDIM * HDIM, HDIM, HDIM, HDIM, m0, n0, smem, tid, acc);

    const int wv = tid >> 6, ln = tid & 63;
    const int wm = wv >> 2, wn = wv & 3;
    const int lane31 = ln & 31, laneHi = ln >> 5;
    const int l0 = m0 & (LDIM - 1);
    u16* T = (u16*)smem;   // [256][264]

    if (z < 2) {
        const u32* CS = (z == 0) ? CSq : CSk;
#pragma unroll
        for (int fn = 0; fn < 2; ++fn) {
            const int gc = n0 + wn * 64 + fn * 32 + lane31;
            const int ih = gc >> 1;
            const float sgn = (gc & 1) ? 1.f : -1.f;
            const u32* tb = CS + (size_t)l0 * 512 + ih;
#pragma unroll
            for (int fm = 0; fm < 4; ++fm) {
#pragma unroll
                for (int reg = 0; reg < 16; ++reg) {
                    const int rowl = wm * 128 + fm * 32 + ROW32(reg, laneHi);
                    u32 v = tb[(size_t)rowl * 512];
                    float cs = __uint_as_float(v << 16);
                    float sn = __uint_as_float(v & 0xFFFF0000u);
                    float c = acc[fm][fn][reg];
                    float p = __shfl_xor(c, 1);   // even<->odd column partner
                    T[rowl * 264 + wn * 64 + fn * 32 + lane31] =
                        f2bf(c * cs + sgn * p * sn);
                }
            }
        }
        __syncthreads();
        u16* Out = (z == 0) ? Qb : Kb;
        const int row_ = tid >> 5, slot = tid & 31;
#pragma unroll
        for (int g = 0; g < 16; ++g) {
            const int row = g * 16 + row_;
            s16x8 v = *(const s16x8*)&T[row * 264 + slot * 8];
            *(s16x8*)&Out[(size_t)(m0 + row) * HDIM + n0 + slot * 8] = v;
        }
    } else {
        // V: repack transposed  T[n_local][m_local]
#pragma unroll
        for (int fn = 0; fn < 2; ++fn)
#pragma unroll
            for (int fm = 0; fm < 4; ++fm)
#pragma unroll
                for (int reg = 0; reg < 16; ++reg)
                    T[(wn * 64 + fn * 32 + lane31) * 264 +
                      wm * 128 + fm * 32 + ROW32(reg, laneHi)] =
                        f2bf(acc[fm][fn][reg]);
        __syncthreads();
        const int b = m0 >> 11;
        const int row_ = tid >> 5, slot = tid & 31;
#pragma unroll
        for (int g = 0; g < 16; ++g) {
            const int row = g * 16 + row_;   // n-local (d index)
            s16x8 v = *(const s16x8*)&T[row * 264 + slot * 8];
            *(s16x8*)&Vt[((size_t)b * HDIM + n0 + row) * LDIM + l0 + slot * 8] = v;
        }
    }
}

// ---------------------------------------------------------------------------
// K2a: W = exp(s)*gamma^|q-k| (bf16) + Z partials (fp32, deterministic).
// grid 512 x 512thr: b = bid&7 (XCD-pinned). decode: nt(8) mt(8) --
// 4MB Q_b hot in XCD L2 across the nt sweep.
// ---------------------------------------------------------------------------
__global__ __launch_bounds__(512, 2) void qk_gemm(
    const u16* __restrict__ Q, const u16* __restrict__ Km,
    u16* __restrict__ Wm, float* __restrict__ Zp)
{
    __shared__ __align__(16) char smem[256 * 264 * 2];
    __shared__ float Zl[4][256];
    const int bid = blockIdx.x;
    const int b = bid & 7, t = bid >> 3;     // t in [0,64)
    const int mt = t & 7;
    const int nt = t >> 3;                   // [0,8)
    const int m0 = mt * 256;
    const int n0 = nt * 256;
    const int tid = threadIdx.x;

    f32x16 acc[4][2] = {};

    gemm256(Q + (size_t)b * LDIM * HDIM, Km + (size_t)b * LDIM * HDIM,
            HDIM, HDIM, HDIM, m0, n0, smem, tid, acc);

    const int wv = tid >> 6, ln = tid & 63;
    const int wm = wv >> 2, wn = wv & 3;
    const int lane31 = ln & 31, laneHi = ln >> 5;
    u16* T = (u16*)smem;   // [256][264]
    const float LOG2E = 1.4426950408889634f;
    const float LOG2G = -0.15200309344504997f;   // log2(0.9)

#pragma unroll
    for (int fm = 0; fm < 4; ++fm) {
        float ps[16];
#pragma unroll
        for (int reg = 0; reg < 16; ++reg) ps[reg] = 0.f;
#pragma unroll
        for (int fn = 0; fn < 2; ++fn) {
            const int gk = n0 + wn * 64 + fn * 32 + lane31;
#pragma unroll
            for (int reg = 0; reg < 16; ++reg) {
                const int mloc = wm * 128 + fm * 32 + ROW32(reg, laneHi);
                const int gq = m0 + mloc;
                float t1 = acc[fm][fn][reg] * LOG2E;
                float e = exp2f(t1);
                int dd = gq - gk; dd = dd < 0 ? -dd : dd;
                ps[reg] += e;
                T[mloc * 264 + wn * 64 + fn * 32 + lane31] =
                    f2bf(exp2f(t1 + (float)dd * LOG2G));
            }
        }
        // reduce e-sums across the 32 column-lanes
#pragma unroll
        for (int reg = 0; reg < 16; ++reg) {
            float s = ps[reg];
            s += __shfl_xor(s, 1); s += __shfl_xor(s, 2);
            s += __shfl_xor(s, 4); s += __shfl_xor(s, 8);
            s += __shfl_xor(s, 16);
            if (lane31 == 0)
                Zl[wn][wm * 128 + fm * 32 + ROW32(reg, laneHi)] = s;
        }
    }
    __syncthreads();

    const int row_ = tid >> 5, slot = tid & 31;
#pragma unroll
    for (int g = 0; g < 16; ++g) {
        const int row = g * 16 + row_;
        s16x8 v = *(const s16x8*)&T[row * 264 + slot * 8];
        *(s16x8*)&Wm[((size_t)b * LDIM + m0 + row) * LDIM + n0 + slot * 8] = v;
    }
    if (tid < 256)
        Zp[((size_t)b * 8 + nt) * LDIM + m0 + tid] =
            Zl[0][tid] + Zl[1][tid] + Zl[2][tid] + Zl[3][tid];
}

// ---------------------------------------------------------------------------
// K2b: O = (W @ V) / Z  (fp32 out).  grid 256 x 512thr: b=bid&7.
// decode: mtH(2) nt(4) mt4(4) -- 4MB W-chunk hot across the nt sweep.
// ---------------------------------------------------------------------------
__global__ __launch_bounds__(512, 2) void pv_gemm(
    const u16* __restrict__ Wm, const u16* __restrict__ Vt,
    const float* __restrict__ Zp, float* __restrict__ Out)
{
    __shared__ __align__(16) char smem[2 * 65536];
    __shared__ float Zinv[256];
    const int bid = blockIdx.x;
    const int b = bid & 7, t = bid >> 3;     // t in [0,32)
    const int mt4 = t & 3;
    const int nt = (t >> 2) & 3;
    const int mtH = t >> 4;                  // {0,1}
    const int m0 = (mtH * 4 + mt4) * 256;
    const int n0 = nt * 256;
    const int tid = threadIdx.x;

    if (tid < 256) {
        float zz = 0.f;
#pragma unroll
        for (int nb = 0; nb < 8; ++nb)
            zz += Zp[((size_t)b * 8 + nb) * LDIM + m0 + tid];
        Zinv[tid] = 1.0f / zz;
    }

    f32x16 acc[4][2] = {};

    gemm256(Wm + (size_t)b * LDIM * LDIM, Vt + (size_t)b * HDIM * LDIM,
            LDIM, LDIM, LDIM, m0, n0, smem, tid, acc);

    const int wv = tid >> 6, ln = tid & 63;
    const int wm = wv >> 2, wn = wv & 3;
    const int lane31 = ln & 31, laneHi = ln >> 5;
    float* Ob = Out + (size_t)b * LDIM * HDIM;
#pragma unroll
    for (int fm = 0; fm < 4; ++fm)
#pragma unroll
        for (int fn = 0; fn < 2; ++fn) {
            const int gn = n0 + wn * 64 + fn * 32 + lane31;
#pragma unroll
            for (int reg = 0; reg < 16; ++reg) {
                const int row = wm * 128 + fm * 32 + ROW32(reg, laneHi);
                Ob[(size_t)(m0 + row) * HDIM + gn] = acc[fm][fn][reg] * Zinv[row];
            }
        }
}

// ---------------------------------------------------------------------------
extern "C" void kernel_launch(void* const* d_in, const int* in_sizes, int n_in,
                              void* d_out, int out_size, void* d_ws, size_t ws_size,
                              hipStream_t stream)
{
    (void)in_sizes; (void)n_in; (void)out_size; (void)ws_size;
    const float* X  = (const float*)d_in[0];
    const float* Wq = (const float*)d_in[1];
    const float* Wk = (const float*)d_in[2];
    const float* Wv = (const float*)d_in[3];
    char* ws = (char*)d_ws;
    const size_t MB = 1024 * 1024;

    u16* Wmat = (u16*)ws;                 // phase2, aliases Xb+WT
    u16* Xb   = (u16*)ws;                 // phase1
    u16* WT   = (u16*)(ws + 32 * MB);     // phase1
    u16* Qb   = (u16*)(ws + 64 * MB);
    u16* Kb   = (u16*)(ws + 96 * MB);
    u16* Vt   = (u16*)(ws + 128 * MB);
    float* Zp = (float*)(ws + 160 * MB);
    u32* CSq  = (u32*)(ws + 161 * MB);
    u32* CSk  = (u32*)(ws + 165 * MB);

    prep_all<<<4864, 256, 0, stream>>>(X, Wq, Wk, Wv, Xb, WT, CSq, CSk);
    qkv_gemm<<<768, 512, 0, stream>>>(Xb, WT, CSq, CSk, Qb, Kb, Vt);
    qk_gemm<<<512, 512, 0, stream>>>(Qb, Kb, Wmat, Zp);
    pv_gemm<<<256, 512, 0, stream>>>(Wmat, Vt, Zp, (float*)d_out);
}